// Round 11
// baseline (118.697 us; speedup 1.0000x reference)
//
#include <hip/hip_runtime.h>

#define N 8192
#define D 128
#define RCH 256                // rows per main block
#define CCH 128                // cols per main block
#define NRC (N / RCH)          // 32 row chunks
#define NCCH (N / CCH)         // 64 col chunks
#define NBIN 81                // labels -1..79 -> bins 0..80
#define PBLK 512               // prep grid (16 rows/block)

typedef unsigned short u16;
typedef __attribute__((ext_vector_type(8))) __bf16 bf16x8;
typedef __attribute__((ext_vector_type(4))) float f32x4;

// scale = sqrt(10 * log2(e)): dot of two scaled rows = log2(e^{cos/T}),
// so e^{sim} = exp2(acc) with NO per-element multiply.
#define PREP_SCALE 3.7982889979f

__device__ __forceinline__ u16 f2bf(float x) {
  unsigned u = __float_as_uint(x);
  u += 0x7fff + ((u >> 16) & 1);  // RNE
  return (u16)(u >> 16);
}

// ---- kernel 1: parallel counting-sort rank + normalize + bf16 write --------
// (proven since R6; single-bf16 absmax 0.0 R4-R10)
__global__ __launch_bounds__(256) void cpe_prep(const float* __restrict__ feat,
                                                const int* __restrict__ labels,
                                                u16* __restrict__ fhi,
                                                int* __restrict__ slab,
                                                float* __restrict__ acc3) {
  __shared__ int hist[4][NBIN], part[4][NBIN], lbase[NBIN], lpos[16];
  const int tid = threadIdx.x;
  const int w = tid >> 6, l = tid & 63;
  const int bid = blockIdx.x;
  if (tid < NBIN) {
#pragma unroll
    for (int cp = 0; cp < 4; ++cp) { hist[cp][tid] = 0; part[cp][tid] = 0; }
  }
  if (bid == 0 && tid < 4) acc3[tid] = 0.0f;
  __syncthreads();
  const int myBase = bid * 16;
  for (int j = tid; j < N; j += 256) {
    const int lab = labels[j] + 1;
    atomicAdd(&hist[w][lab], 1);
    if (j < myBase) atomicAdd(&part[w][lab], 1);
  }
  __syncthreads();
  if (tid < NBIN) {
    hist[0][tid] += hist[1][tid] + hist[2][tid] + hist[3][tid];
    part[0][tid] += part[1][tid] + part[2][tid] + part[3][tid];
  }
  __syncthreads();
  if (tid == 0) {
    int s = 0;
    for (int b = 0; b < NBIN; ++b) { lbase[b] = s; s += hist[0][b]; }
  }
  __syncthreads();
  if (tid < 16) {
    const int L = labels[myBase + tid] + 1;
    int pos = lbase[L] + part[0][L];
    for (int k = 0; k < tid; ++k) pos += (labels[myBase + k] + 1 == L) ? 1 : 0;
    lpos[tid] = pos;
    slab[pos] = L - 1;
  }
  __syncthreads();
#pragma unroll
  for (int rr = 0; rr < 4; ++rr) {
    const int k = w * 4 + rr;
    const float2 x = *(const float2*)&feat[(myBase + k) * D + l * 2];
    float s = x.x * x.x + x.y * x.y;
#pragma unroll
    for (int sh = 1; sh < 64; sh <<= 1) s += __shfl_xor(s, sh);
    const float inv = PREP_SCALE / fmaxf(sqrtf(s), 1e-12f);
    const int pos = lpos[k];
    *(ushort2*)&fhi[pos * D + l * 2] = make_ushort2(f2bf(x.x * inv), f2bf(x.y * inv));
  }
}

// ---- kernel 2: SYMMETRIC fused sim: upper-triangle chunk pairs only --------
// sim and all masks are symmetric -> compute each off-diagonal chunk tile
// ONCE, credit rows via row-sums (as before) AND the mirrored rows via
// column-sums (2x shfl_xor over q-groups + per-tile register stash + 4KB LDS
// cross-wave combine). Halves MFMA/ds_read/exp2/staging.
// Grid: 1D 1056 = pairs (rt 0..31 of 256 rows, cc 0..63 of 128 cols) with
// cc >= 2*rt. Per (wave,tr,tile) wave-uniform 3-way: jbase>rowbase ->
// row+col; == -> diagonal tile (row-only, self-excluded; mirror is in-tile);
// < -> skip (mirror handled by the transposed block).
// partA[cc][row] = row-side partial; partB[rt][col] = col-side partial.
// Every slot that cpe_rows reads is written exactly once (poison-safe).
__global__ __launch_bounds__(256, 2) void cpe_main(
    const u16* __restrict__ fhi, const int* __restrict__ slab,
    float2* __restrict__ partA, float2* __restrict__ partB) {
  __shared__ __align__(16) u16 Bh[2][64 * 128];  // 2 x 16 KB, XOR-swizzled
  __shared__ int Lab[CCH];                       // col labels (512 B)
  __shared__ float LcA[4][CCH], LcP[4][CCH];     // per-wave col-sums (4 KB)
  const int tid = threadIdx.x;
  const int w = tid >> 6, l = tid & 63, q = l >> 4, m = l & 15;

  // bid -> (rt, cc) with cc >= 2*rt (wave-uniform scalar loop, <=32 iters)
  int b = blockIdx.x, rt = 0;
  while (b >= NCCH - 2 * rt) { b -= NCCH - 2 * rt; ++rt; }
  const int cc = 2 * rt + b;
  const int r0 = rt * RCH, cbase0 = cc * CCH;
  const int r0w = r0 + w * 64;

#define STAGE(buf, ht)                                                         \
  do {                                                                         \
    const int cb_ = cbase0 + (ht) * 64;                                        \
    _Pragma("unroll") for (int n = 0; n < 4; ++n) {                            \
      const int r_ = w * 16 + n * 4 + q;                                       \
      const int c_ = m ^ (r_ & 15);                                            \
      const u16* gh_ = &fhi[(size_t)(cb_ + r_) * D + c_ * 8];                  \
      __builtin_amdgcn_global_load_lds(                                        \
          (const __attribute__((address_space(1))) unsigned*)gh_,              \
          (__attribute__((address_space(3))) unsigned*)&Bh[buf][(w * 256 + n * 64) * 8], \
          16, 0, 0);                                                           \
    }                                                                          \
  } while (0)

  STAGE(0, 0);  // prologue: half-tile 0 in flight while Lab/A-frags load

  if (tid < CCH) Lab[tid] = slab[cbase0 + tid];

  const int labi_lo = slab[r0w], labi_hi = slab[r0w + 63];

  bf16x8 Ah[4][4];
  int labi[4][4];
#pragma unroll
  for (int tr = 0; tr < 4; ++tr) {
    const int row = r0w + tr * 16 + m;
#pragma unroll
    for (int ks = 0; ks < 4; ++ks)
      Ah[tr][ks] = *(const bf16x8*)&fhi[row * D + ks * 32 + q * 8];
#pragma unroll
    for (int v = 0; v < 4; ++v) labi[tr][v] = slab[r0w + tr * 16 + q * 4 + v];
  }

  float ps[4][4], as_[4][4];
#pragma unroll
  for (int tr = 0; tr < 4; ++tr)
#pragma unroll
    for (int v = 0; v < 4; ++v) { ps[tr][v] = 0.f; as_[tr][v] = 0.f; }
  // per-tile column-sum register stash: slot (q, k) holds col (q*2+k)*16+m
  float csA0 = 0.f, csA1 = 0.f, csP0 = 0.f, csP1 = 0.f;

  __syncthreads();  // Lab ready + half-tile 0 staged

#pragma unroll
  for (int ht = 0; ht < 2; ++ht) {
    if (ht == 0) STAGE(1, 1);  // overlap second half-tile under first compute

#pragma unroll
    for (int ctl = 0; ctl < 4; ++ctl) {
      const int tct = ht * 4 + ctl;      // static (fully unrolled)
      const int tb = tct * 16;
      const int jbase = cbase0 + tb;
      const int labj_lo = Lab[tb], labj_hi = Lab[tb + 15];
      // all-bg cols, or entirely below this wave's diagonal -> nothing
      if (labj_hi < 0 || jbase < r0w) continue;

      f32x4 acc[4];
#pragma unroll
      for (int tr = 0; tr < 4; ++tr) acc[tr] = (f32x4){0.f, 0.f, 0.f, 0.f};
#pragma unroll
      for (int ks = 0; ks < 4; ++ks) {
        const int off = (ctl * 16 + m) * 128 + ((ks * 4 + q) ^ m) * 8;
        const bf16x8 bh = *(const bf16x8*)&Bh[ht][off];
#pragma unroll
        for (int tr = 0; tr < 4; ++tr)
          acc[tr] = __builtin_amdgcn_mfma_f32_16x16x32_bf16(Ah[tr][ks], bh, acc[tr], 0, 0, 0);
      }

      float cAs = 0.f, cPs = 0.f;  // this tile's col-sums (col = jbase + m)
      const bool slow = (labj_lo < 0) | ((labj_hi >= labi_lo) & (labj_lo <= labi_hi));
      if (!slow) {
        // fast: all-fg, label-disjoint -> no positives either side, no self
#pragma unroll
        for (int tr = 0; tr < 4; ++tr) {
          if (jbase > r0w + tr * 16) {  // skip lower tr (mirror elsewhere)
#pragma unroll
            for (int v = 0; v < 4; ++v) {
              const float e = __builtin_amdgcn_exp2f(acc[tr][v]);
              as_[tr][v] += e;
              cAs += (labi[tr][v] >= 0) ? e : 0.f;  // mask bg rows col-side
            }
          }
        }
      } else {
        const int labj = Lab[tb + m];
        const bool fgj = labj >= 0;
#pragma unroll
        for (int tr = 0; tr < 4; ++tr) {
          const int rowbase = r0w + tr * 16;
          if (jbase > rowbase) {  // strict upper: row + col credit
#pragma unroll
            for (int v = 0; v < 4; ++v) {
              const float e = __builtin_amdgcn_exp2f(acc[tr][v]);
              const bool eq = (labj == labi[tr][v]);
              const float em = fgj ? e : 0.f;
              as_[tr][v] += em;
              ps[tr][v] += eq ? em : 0.f;
              const float emc = (labi[tr][v] >= 0) ? e : 0.f;
              cAs += emc;
              cPs += eq ? emc : 0.f;
            }
          } else if (jbase == rowbase) {  // diagonal tile: row-only
#pragma unroll
            for (int v = 0; v < 4; ++v) {
              const float e = __builtin_amdgcn_exp2f(acc[tr][v]);
              const float em = (fgj && (m != q * 4 + v)) ? e : 0.f;
              as_[tr][v] += em;
              ps[tr][v] += (labj == labi[tr][v]) ? em : 0.f;
            }
          }  // else lower: skip (mirror computed by transposed block)
        }
      }
      // reduce col-sums over the 4 q-groups; stash in this tile's slot
      cAs += __shfl_xor(cAs, 16); cAs += __shfl_xor(cAs, 32);
      cPs += __shfl_xor(cPs, 16); cPs += __shfl_xor(cPs, 32);
      if ((tct >> 1) == q) {
        if ((tct & 1) == 0) { csA0 = cAs; csP0 = cPs; }
        else               { csA1 = cAs; csP1 = cPs; }
      }
    }
    __syncthreads();  // half-tile consumed; next half staged (vmcnt drained)
  }
#undef STAGE

  // row-side partials: reduce over the 16 m-lanes; write partA[cc][row]
#pragma unroll
  for (int tr = 0; tr < 4; ++tr)
#pragma unroll
    for (int v = 0; v < 4; ++v) {
      float vp = ps[tr][v], va = as_[tr][v];
#pragma unroll
      for (int s = 1; s < 16; s <<= 1) {
        vp += __shfl_xor(vp, s);
        va += __shfl_xor(va, s);
      }
      if (m == 0)
        partA[(size_t)cc * N + r0w + tr * 16 + q * 4 + v] = make_float2(vp, va);
    }

  // col-side partials: cross-wave combine via LDS; write partB[rt][col]
  LcA[w][(q * 2 + 0) * 16 + m] = csA0;
  LcA[w][(q * 2 + 1) * 16 + m] = csA1;
  LcP[w][(q * 2 + 0) * 16 + m] = csP0;
  LcP[w][(q * 2 + 1) * 16 + m] = csP1;
  __syncthreads();
  if (tid < CCH) {
    const float a = LcA[0][tid] + LcA[1][tid] + LcA[2][tid] + LcA[3][tid];
    const float p = LcP[0][tid] + LcP[1][tid] + LcP[2][tid] + LcP[3][tid];
    partB[(size_t)rt * N + cbase0 + tid] = make_float2(p, a);
  }
}

// ---- kernel 3: combine partials -> per-row loss -> mean (self-finalizing) --
// Row r (chunk rtb = r>>8): row-side slots k = 2*rtb..63 (blocks (rtb,k));
// col-side slots t = 0..rtb (blocks (t, cc_r)). All written by construction.
__global__ __launch_bounds__(256) void cpe_rows(const float2* __restrict__ partA,
                                                const float2* __restrict__ partB,
                                                const int* __restrict__ slab,
                                                float* __restrict__ acc3,
                                                float* __restrict__ out) {
  const int rtb = blockIdx.x;
  const int r = rtb * 256 + threadIdx.x;
  float psr = 0.f, asr = 0.f;
  for (int k = 2 * rtb; k < NCCH; ++k) {
    const float2 p = partA[(size_t)k * N + r];
    psr += p.x; asr += p.y;
  }
  for (int t = 0; t <= rtb; ++t) {
    const float2 p = partB[(size_t)t * N + r];
    psr += p.x; asr += p.y;
  }
  const bool fg = slab[r] >= 0;
  const bool valid = fg && (psr > 0.f);
  const float loss = fminf(logf(asr / psr), 10.0f);
  float v0 = valid ? loss : 0.f;
  float v1 = valid ? 1.f : 0.f;
  float v2 = fg ? 1.f : 0.f;
#pragma unroll
  for (int s = 1; s < 64; s <<= 1) {
    v0 += __shfl_xor(v0, s);
    v1 += __shfl_xor(v1, s);
    v2 += __shfl_xor(v2, s);
  }
  __shared__ float red[3][4];
  const int w = threadIdx.x >> 6, l = threadIdx.x & 63;
  if (l == 0) { red[0][w] = v0; red[1][w] = v1; red[2][w] = v2; }
  __syncthreads();
  if (threadIdx.x == 0) {
    atomicAdd(&acc3[0], red[0][0] + red[0][1] + red[0][2] + red[0][3]);
    atomicAdd(&acc3[1], red[1][0] + red[1][1] + red[1][2] + red[1][3]);
    atomicAdd(&acc3[2], red[2][0] + red[2][1] + red[2][2] + red[2][3]);
    __threadfence();
    const unsigned old = atomicAdd((unsigned*)&acc3[3], 1u);
    if (old == gridDim.x - 1) {
      const float ls = atomicAdd(&acc3[0], 0.0f);
      const float nv = atomicAdd(&acc3[1], 0.0f);
      const float nf = atomicAdd(&acc3[2], 0.0f);
      out[0] = (nf >= 2.0f && nv > 0.0f) ? ls / fmaxf(nv, 1.0f) : 0.0f;
    }
  }
}

extern "C" void kernel_launch(void* const* d_in, const int* in_sizes, int n_in,
                              void* d_out, int out_size, void* d_ws, size_t ws_size,
                              hipStream_t stream) {
  const float* feat = (const float*)d_in[0];
  const int* labels = (const int*)d_in[1];
  float* out = (float*)d_out;
  char* ws = (char*)d_ws;
  u16* fhi = (u16*)ws;                                        // 2 MB
  float2* partA = (float2*)(ws + (size_t)N * D * 2);          // 4 MB (64 slots)
  float2* partB = (float2*)(ws + (size_t)N * D * 2 + (size_t)NCCH * N * 8);  // 2 MB
  char* tail = ws + (size_t)N * D * 2 + (size_t)(NCCH + NRC) * N * 8;
  int* slab = (int*)tail;                                     // 32 KB
  float* acc3 = (float*)(tail + N * 4);                       // 4 f32

  const int nblk = 1056;  // sum_{rt=0}^{31} (64 - 2*rt)
  cpe_prep<<<PBLK, 256, 0, stream>>>(feat, labels, fhi, slab, acc3);
  cpe_main<<<nblk, 256, 0, stream>>>(fhi, slab, partA, partB);
  cpe_rows<<<NRC, 256, 0, stream>>>(partA, partB, slab, acc3, out);
}

// Round 12
// 102.159 us; speedup vs baseline: 1.1619x; 1.1619x over previous
//
#include <hip/hip_runtime.h>

#define N 8192
#define D 128
#define CHUNK 512
#define NCC (N / CHUNK)        // 16 column chunks
#define TILE_IT (CHUNK / 128)  // 4 B-tiles per chunk
#define RROWS 512              // rows per main block (8 waves)
#define NBIN 81                // labels -1..79 -> bins 0..80
#define PBLK 512               // prep grid (16 rows/block)

typedef unsigned short u16;
typedef __attribute__((ext_vector_type(8))) __bf16 bf16x8;
typedef __attribute__((ext_vector_type(4))) float f32x4;

// scale = sqrt(10 * log2(e)): dot of two scaled rows = log2(e^{cos/T}),
// so e^{sim} = exp2(acc) with NO per-element multiply.
#define PREP_SCALE 3.7982889979f

__device__ __forceinline__ u16 f2bf(float x) {
  unsigned u = __float_as_uint(x);
  u += 0x7fff + ((u >> 16) & 1);  // RNE
  return (u16)(u >> 16);
}

// ---- kernel 1: parallel counting-sort rank + normalize + bf16 write --------
// (proven since R6; single-bf16 absmax 0.0 R4-R11)
__global__ __launch_bounds__(256) void cpe_prep(const float* __restrict__ feat,
                                                const int* __restrict__ labels,
                                                u16* __restrict__ fhi,
                                                int* __restrict__ slab,
                                                float* __restrict__ acc3) {
  __shared__ int hist[4][NBIN], part[4][NBIN], lbase[NBIN], lpos[16];
  const int tid = threadIdx.x;
  const int w = tid >> 6, l = tid & 63;
  const int bid = blockIdx.x;
  if (tid < NBIN) {
#pragma unroll
    for (int cp = 0; cp < 4; ++cp) { hist[cp][tid] = 0; part[cp][tid] = 0; }
  }
  if (bid == 0 && tid < 4) acc3[tid] = 0.0f;
  __syncthreads();
  const int myBase = bid * 16;
  for (int j = tid; j < N; j += 256) {
    const int lab = labels[j] + 1;
    atomicAdd(&hist[w][lab], 1);
    if (j < myBase) atomicAdd(&part[w][lab], 1);
  }
  __syncthreads();
  if (tid < NBIN) {
    hist[0][tid] += hist[1][tid] + hist[2][tid] + hist[3][tid];
    part[0][tid] += part[1][tid] + part[2][tid] + part[3][tid];
  }
  __syncthreads();
  if (tid == 0) {
    int s = 0;
    for (int b = 0; b < NBIN; ++b) { lbase[b] = s; s += hist[0][b]; }
  }
  __syncthreads();
  if (tid < 16) {
    const int L = labels[myBase + tid] + 1;
    int pos = lbase[L] + part[0][L];
    for (int k = 0; k < tid; ++k) pos += (labels[myBase + k] + 1 == L) ? 1 : 0;
    lpos[tid] = pos;
    slab[pos] = L - 1;
  }
  __syncthreads();
#pragma unroll
  for (int rr = 0; rr < 4; ++rr) {
    const int k = w * 4 + rr;
    const float2 x = *(const float2*)&feat[(myBase + k) * D + l * 2];
    float s = x.x * x.x + x.y * x.y;
#pragma unroll
    for (int sh = 1; sh < 64; sh <<= 1) s += __shfl_xor(s, sh);
    const float inv = PREP_SCALE / fmaxf(sqrtf(s), 1e-12f);
    const int pos = lpos[k];
    *(ushort2*)&fhi[pos * D + l * 2] = make_ushort2(f2bf(x.x * inv), f2bf(x.y * inv));
  }
}

// ---- kernel 2: fused sim + masked reductions, counted-vmcnt pipeline -------
// vs R9 (same math, same per-wave tiles): (1) T4 counted vmcnt — R9's
// __syncthreads drained vmcnt(0) per tile, m218's measured null pattern;
// now raw s_barrier + s_waitcnt vmcnt(4), drain 0 only at the last tile, so
// next-tile DMA stays in flight ACROSS the barrier. (2) 512-row blocks
// (512 thr, 8 waves): B-tile shared by 8 waves -> stage bytes & events
// halved; grid 16x16 = 256 blocks = exactly 1/CU, zero tail imbalance.
// No launch_bounds reg-cap (R4 spill lesson); ~96 VGPR -> 8 waves/CU.
// SORTED label order fast path; loss = log(as/ps) (clips provably inactive).
__global__ __launch_bounds__(512) void cpe_main(
    const u16* __restrict__ fhi, const int* __restrict__ slab,
    float2* __restrict__ partials) {
  __shared__ __align__(16) u16 Bh[2][128 * 128];  // 2 x 32 KB, XOR-swizzled
  __shared__ int Lab[CHUNK];                      // 2 KB
  const int rt = blockIdx.x, cc = blockIdx.y;     // grid (16,16)
  const int tid = threadIdx.x;
  const int w = tid >> 6, l = tid & 63, q = l >> 4, m = l & 15;
  const int r0w = rt * RROWS + w * 64;
  const int cbase0 = cc * CHUNK;

  // stage a 128-col tile (32 KB): 512 thr x 16B x 4 rounds. LDS slot
  // p = w*256 + n*64 + lane -> (r = p>>4, c' = p&15 = m); c = c' ^ (r&15).
#define STAGE(buf, itv)                                                        \
  do {                                                                         \
    const int cbase_ = cbase0 + (itv) * 128;                                   \
    _Pragma("unroll") for (int n = 0; n < 4; ++n) {                            \
      const int r_ = w * 16 + n * 4 + q;                                       \
      const int c_ = m ^ (r_ & 15);                                            \
      const u16* gh_ = &fhi[(size_t)(cbase_ + r_) * D + c_ * 8];               \
      __builtin_amdgcn_global_load_lds(                                        \
          (const __attribute__((address_space(1))) unsigned*)gh_,              \
          (__attribute__((address_space(3))) unsigned*)&Bh[buf][(w * 256 + n * 64) * 8], \
          16, 0, 0);                                                           \
    }                                                                          \
  } while (0)

  Lab[tid] = slab[cbase0 + tid];  // 512 threads cover CHUNK=512

  // wave-uniform row-label range (labels sorted ascending)
  const int labi_lo = slab[r0w], labi_hi = slab[r0w + 63];

  // A fragments + row labels straight from global (L2-resident, once).
  // Issued BEFORE the stages so compiler A-waits never drain stage loads.
  bf16x8 Ah[4][4];
  int labi[4][4];
#pragma unroll
  for (int tr = 0; tr < 4; ++tr) {
    const int row = r0w + tr * 16 + m;
#pragma unroll
    for (int ks = 0; ks < 4; ++ks)
      Ah[tr][ks] = *(const bf16x8*)&fhi[row * D + ks * 32 + q * 8];
#pragma unroll
    for (int v = 0; v < 4; ++v) labi[tr][v] = slab[r0w + tr * 16 + q * 4 + v];
  }

  float ps[4][4], as_[4][4];
#pragma unroll
  for (int tr = 0; tr < 4; ++tr)
#pragma unroll
    for (int v = 0; v < 4; ++v) { ps[tr][v] = 0.f; as_[tr][v] = 0.f; }

  __builtin_amdgcn_sched_barrier(0);  // pin: A/Lab loads above, stages below
  STAGE(0, 0);                        // tile 0 in flight (NOT drained)

  // Lab ds_writes visible to all waves; stages stay outstanding (no vmcnt).
  asm volatile("s_waitcnt lgkmcnt(0)" ::: "memory");
  __builtin_amdgcn_s_barrier();
  __builtin_amdgcn_sched_barrier(0);

#pragma unroll
  for (int it = 0; it < TILE_IT; ++it) {
    const int cur = it & 1;
    if (it > 0) {
      // (A) all waves done reading Bh[cur] from iteration it-1's sibling —
      // safe to overwrite it with tile it+1. No vmcnt drain here.
      asm volatile("s_waitcnt lgkmcnt(0)" ::: "memory");
      __builtin_amdgcn_s_barrier();
      __builtin_amdgcn_sched_barrier(0);
    }
    if (it + 1 < TILE_IT) STAGE(cur ^ 1, it + 1);
    // (B) tile `cur` landed: counted wait leaves the 4 just-issued next-tile
    // loads in flight (T4 — never drain to 0 mid-loop).
    if (it + 1 < TILE_IT)
      asm volatile("s_waitcnt vmcnt(4)" ::: "memory");
    else
      asm volatile("s_waitcnt vmcnt(0)" ::: "memory");
    __builtin_amdgcn_s_barrier();
    __builtin_amdgcn_sched_barrier(0);

    const int cbase = cbase0 + it * 128;
    for (int ct = 0; ct < 8; ++ct) {
      const int tb = it * 128 + ct * 16;
      const int labj_lo = Lab[tb], labj_hi = Lab[tb + 15];
      if (labj_hi < 0) continue;  // all-bg tile: every em==0, skip MFMA too
      const bool slow = (labj_lo < 0) | ((labj_hi >= labi_lo) & (labj_lo <= labi_hi));
      const int jj = ct * 16 + m;
      f32x4 acc[4];
#pragma unroll
      for (int tr = 0; tr < 4; ++tr) acc[tr] = (f32x4){0.f, 0.f, 0.f, 0.f};
#pragma unroll
      for (int ks = 0; ks < 4; ++ks) {
        const int off = jj * 128 + ((ks * 4 + q) ^ m) * 8;  // swizzled chunk
        const bf16x8 bh = *(const bf16x8*)&Bh[cur][off];
#pragma unroll
        for (int tr = 0; tr < 4; ++tr)
          acc[tr] = __builtin_amdgcn_mfma_f32_16x16x32_bf16(Ah[tr][ks], bh, acc[tr], 0, 0, 0);
      }
      if (!slow) {
        // fast path (~97% of tiles): all-fg, no positives, no self
#pragma unroll
        for (int tr = 0; tr < 4; ++tr)
#pragma unroll
          for (int v = 0; v < 4; ++v)
            as_[tr][v] += __builtin_amdgcn_exp2f(acc[tr][v]);
      } else {
        const int labj = Lab[tb + m];
        const bool fgj = labj >= 0;
        const int jbase = cbase + ct * 16;
#pragma unroll
        for (int tr = 0; tr < 4; ++tr) {
          if (jbase == r0w + tr * 16) {  // wave-uniform diagonal-tile branch
#pragma unroll
            for (int v = 0; v < 4; ++v) {
              const float e = __builtin_amdgcn_exp2f(acc[tr][v]);
              const float em = (fgj && (m != q * 4 + v)) ? e : 0.0f;
              as_[tr][v] += em;
              ps[tr][v] += (labj == labi[tr][v]) ? em : 0.0f;
            }
          } else {
#pragma unroll
            for (int v = 0; v < 4; ++v) {
              const float e = __builtin_amdgcn_exp2f(acc[tr][v]);
              const float em = fgj ? e : 0.0f;
              as_[tr][v] += em;
              ps[tr][v] += (labj == labi[tr][v]) ? em : 0.0f;
            }
          }
        }
      }
    }
  }
#undef STAGE

  // reduce across the 16 lanes (m) of each quad; plain float2 store per row
#pragma unroll
  for (int tr = 0; tr < 4; ++tr)
#pragma unroll
    for (int v = 0; v < 4; ++v) {
      float vp = ps[tr][v], va = as_[tr][v];
#pragma unroll
      for (int s = 1; s < 16; s <<= 1) {
        vp += __shfl_xor(vp, s);
        va += __shfl_xor(va, s);
      }
      if (m == 0)
        partials[(size_t)cc * N + r0w + tr * 16 + q * 4 + v] = make_float2(vp, va);
    }
}

// ---- kernel 3: combine partials -> per-row loss -> mean (self-finalizing) --
__global__ __launch_bounds__(256) void cpe_rows(const float2* __restrict__ partials,
                                                const int* __restrict__ slab,
                                                float* __restrict__ acc3,
                                                float* __restrict__ out) {
  const int r = blockIdx.x * 256 + threadIdx.x;
  float psr = 0.f, asr = 0.f;
#pragma unroll
  for (int c = 0; c < NCC; ++c) {
    const float2 p = partials[(size_t)c * N + r];
    psr += p.x;
    asr += p.y;
  }
  const bool fg = slab[r] >= 0;
  const bool valid = fg && (psr > 0.f);  // e>0 => (npos>0 <=> ps>0)
  const float loss = fminf(logf(asr / psr), 10.0f);
  float v0 = valid ? loss : 0.f;
  float v1 = valid ? 1.f : 0.f;
  float v2 = fg ? 1.f : 0.f;
#pragma unroll
  for (int s = 1; s < 64; s <<= 1) {
    v0 += __shfl_xor(v0, s);
    v1 += __shfl_xor(v1, s);
    v2 += __shfl_xor(v2, s);
  }
  __shared__ float red[3][4];
  const int w = threadIdx.x >> 6, l = threadIdx.x & 63;
  if (l == 0) { red[0][w] = v0; red[1][w] = v1; red[2][w] = v2; }
  __syncthreads();
  if (threadIdx.x == 0) {
    atomicAdd(&acc3[0], red[0][0] + red[0][1] + red[0][2] + red[0][3]);
    atomicAdd(&acc3[1], red[1][0] + red[1][1] + red[1][2] + red[1][3]);
    atomicAdd(&acc3[2], red[2][0] + red[2][1] + red[2][2] + red[2][3]);
    __threadfence();
    const unsigned old = atomicAdd((unsigned*)&acc3[3], 1u);
    if (old == gridDim.x - 1) {  // last block finalizes (device-scope reads)
      const float ls = atomicAdd(&acc3[0], 0.0f);
      const float nv = atomicAdd(&acc3[1], 0.0f);
      const float nf = atomicAdd(&acc3[2], 0.0f);
      out[0] = (nf >= 2.0f && nv > 0.0f) ? ls / fmaxf(nv, 1.0f) : 0.0f;
    }
  }
}

extern "C" void kernel_launch(void* const* d_in, const int* in_sizes, int n_in,
                              void* d_out, int out_size, void* d_ws, size_t ws_size,
                              hipStream_t stream) {
  const float* feat = (const float*)d_in[0];
  const int* labels = (const int*)d_in[1];
  float* out = (float*)d_out;
  char* ws = (char*)d_ws;
  u16* fhi = (u16*)ws;                                    // 2 MB
  float2* partials = (float2*)(ws + (size_t)N * D * 2);   // 1 MB (16 chunks)
  char* tail = ws + (size_t)N * D * 2 + (size_t)NCC * N * 8;
  int* slab = (int*)tail;                                 // 32 KB
  float* acc3 = (float*)(tail + N * 4);                   // 4 f32

  cpe_prep<<<PBLK, 256, 0, stream>>>(feat, labels, fhi, slab, acc3);
  cpe_main<<<dim3(N / RROWS, NCC), 512, 0, stream>>>(fhi, slab, partials);
  cpe_rows<<<N / 256, 256, 0, stream>>>(partials, slab, acc3, out);
}